// Round 10
// baseline (828.746 us; speedup 1.0000x reference)
//
#include <hip/hip_runtime.h>

#define N_NODES 4096
#define HID 64
#define NH (N_NODES * HID)
#define NPART 8

typedef float f32x4 __attribute__((ext_vector_type(4)));
typedef short s16x4 __attribute__((ext_vector_type(4)));
typedef short s16x8 __attribute__((ext_vector_type(8)));

__device__ __forceinline__ short f2bf(float f) {
    union { float f; unsigned u; } v; v.f = f;
    unsigned r = v.u + 0x7fffu + ((v.u >> 16) & 1u);  // RTNE
    return (short)(r >> 16);
}

// K1: S = h @ w_self (p==8), BT[r][e][m] = (h @ w_rel[r])[m][e] as bf16 (p<8)
__global__ __launch_bounds__(256) void proj_kernel(
    const float* __restrict__ h, const float* __restrict__ w_self_l,
    const float* __restrict__ w_rel_l, float* __restrict__ S,
    short* __restrict__ BT)
{
    __shared__ float hs[64][65];
    __shared__ float wt[64][64];
    const int tid = threadIdx.x;
    const int mb = blockIdx.x;
    const int p = blockIdx.y;
    const float* w = (p < 8) ? (w_rel_l + p * 64 * 64) : w_self_l;

    #pragma unroll
    for (int i = 0; i < 4; ++i) {
        int idx4 = tid + 256 * i;
        int row = idx4 >> 4, c = idx4 & 15;
        float4 v = *((const float4*)(h + (size_t)(mb * 64 + row) * HID) + c);
        hs[row][c * 4 + 0] = v.x; hs[row][c * 4 + 1] = v.y;
        hs[row][c * 4 + 2] = v.z; hs[row][c * 4 + 3] = v.w;
    }
    #pragma unroll
    for (int i = 0; i < 4; ++i) {
        int idx4 = tid + 256 * i;
        ((float4*)wt)[idx4] = ((const float4*)w)[idx4];
    }
    __syncthreads();

    const int m = tid & 63;
    const int eb = (tid >> 6) * 16;   // wave-uniform
    float acc[16];
    #pragma unroll
    for (int j = 0; j < 16; ++j) acc[j] = 0.f;

    #pragma unroll 4
    for (int d = 0; d < 64; ++d) {
        float hv = hs[m][d];
        const float4* wr = (const float4*)&wt[d][eb];
        float4 w0 = wr[0], w1 = wr[1], w2 = wr[2], w3 = wr[3];
        acc[0]  += hv * w0.x; acc[1]  += hv * w0.y; acc[2]  += hv * w0.z; acc[3]  += hv * w0.w;
        acc[4]  += hv * w1.x; acc[5]  += hv * w1.y; acc[6]  += hv * w1.z; acc[7]  += hv * w1.w;
        acc[8]  += hv * w2.x; acc[9]  += hv * w2.y; acc[10] += hv * w2.z; acc[11] += hv * w2.w;
        acc[12] += hv * w3.x; acc[13] += hv * w3.y; acc[14] += hv * w3.z; acc[15] += hv * w3.w;
    }

    if (p < 8) {
        #pragma unroll
        for (int j = 0; j < 16; ++j)
            BT[(size_t)(p * 64 + eb + j) * N_NODES + mb * 64 + m] = f2bf(acc[j]);
    } else {
        #pragma unroll
        for (int j = 0; j < 16; ++j)
            S[(size_t)(mb * 64 + m) * HID + eb + j] = acc[j];
    }
}

// K2: HBM-stream-shaped MFMA GEMM.
//   R8 post-mortem: 3 structurally different schedules all ~2.5 TB/s effective
//   -> bottleneck is the ADDRESS STREAM, not the pipeline. Old: per XCD 8192
//   concurrent 256B-granular row streams (128 blocks x 64 rows) -> HBM
//   row-buffer thrash. New: no ks-split (grid 512), per block 4 row-group
//   phases of 16 rows x full K=4096, BK=128 -> per XCD 1024 streams (8x
//   fewer) of 512B sequential chunks. B is L2-resident (512KB/XCD),
//   re-staged per phase from L2 (no HBM cost).
//   Waves split the N dim (wave = nb); A-frags broadcast to all 4 waves.
//   Same R8 pipeline: reg-staged loads, raw s_barrier + lgkmcnt(0) only
//   (no vmcnt drain at barriers), f2bf at staging, odd-slot-stride padding
//   (136 shorts = 17 x 16B slots -> frag reads at the b128 floor).
// Partials: 8 (one per relation r); every output word written by ONE block.
__global__ __launch_bounds__(256, 3) void gemm_kernel(
    const float* __restrict__ A, const short* __restrict__ BT,
    float* __restrict__ msg)
{
    __shared__ __attribute__((aligned(16))) short As[2][16 * 136];  // 8.7 KB
    __shared__ __attribute__((aligned(16))) short Bs[2][64 * 136];  // 34.8 KB

    const int tid = threadIdx.x;
    const int gid = blockIdx.x;
    const int r  = gid & 7;          // relation -> XCD (L2 locality for BT)
    const int rb = gid >> 3;         // 64-row tile (0..63)
    const int wave = tid >> 6, lane = tid & 63;
    const int quad = lane >> 4, l16 = lane & 15;

    // staging maps (adjacent lanes contiguous)
    const int rA = tid >> 4, cA = tid & 15;  // A: 16 rows, 2 sets of 16 chunks
    const int rB = tid >> 2, cB = tid & 3;   // B: 64 rows, 4 sets of 4 chunks
    const float* Ag = A  + ((size_t)r * N_NODES + rb * 64) * N_NODES;
    const short* Bg = BT + (size_t)r * 64 * N_NODES;

    f32x4 acc = (f32x4){0.f, 0.f, 0.f, 0.f};

    f32x4 a_nx[2];
    s16x8 b_nx[4];
    auto load_tile = [&](int u) {           // u = phase*32 + t
        const int ph = u >> 5;
        const int k0 = (u & 31) * 128;
        #pragma unroll
        for (int s = 0; s < 2; ++s)
            a_nx[s] = __builtin_nontemporal_load(
                (const f32x4*)(Ag + (size_t)(ph * 16 + rA) * N_NODES + k0 + cA * 4 + s * 64));
        #pragma unroll
        for (int s = 0; s < 4; ++s)
            b_nx[s] = *(const s16x8*)(Bg + (size_t)rB * N_NODES + k0 + cB * 8 + s * 32);
    };
    auto write_tile = [&](int b) {
        #pragma unroll
        for (int s = 0; s < 2; ++s) {
            s16x4 av;
            av[0] = f2bf(a_nx[s][0]); av[1] = f2bf(a_nx[s][1]);
            av[2] = f2bf(a_nx[s][2]); av[3] = f2bf(a_nx[s][3]);
            *(s16x4*)&As[b][rA * 136 + cA * 4 + s * 64] = av;
        }
        #pragma unroll
        for (int s = 0; s < 4; ++s)
            *(s16x8*)&Bs[b][rB * 136 + cB * 8 + s * 32] = b_nx[s];
    };

    load_tile(0);
    write_tile(0);                   // vmcnt wait at use (compiler-placed)
    load_tile(1);                    // tile 1 in flight across barrier
    asm volatile("s_waitcnt lgkmcnt(0)" ::: "memory");
    __builtin_amdgcn_s_barrier();

    float* mo = msg + (size_t)r * NH;

    #pragma unroll 2
    for (int u = 0; u < 128; ++u) {
        const int b = u & 1;
        #pragma unroll
        for (int kk = 0; kk < 4; ++kk) {
            s16x8 af  = *(const s16x8*)&As[b][l16 * 136 + kk * 32 + quad * 8];
            s16x8 bfr = *(const s16x8*)&Bs[b][(wave * 16 + l16) * 136 + kk * 32 + quad * 8];
            acc = __builtin_amdgcn_mfma_f32_16x16x32_bf16(af, bfr, acc, 0, 0, 0);
        }
        if ((u & 31) == 31) {        // end of row-group phase: flush 16x64
            const int ph = u >> 5;
            #pragma unroll
            for (int i = 0; i < 4; ++i) {
                int orow = rb * 64 + ph * 16 + quad * 4 + i;
                mo[(size_t)orow * HID + wave * 16 + l16] = acc[i];
            }
            acc = (f32x4){0.f, 0.f, 0.f, 0.f};
        }
        if (u < 127) {
            __builtin_amdgcn_sched_barrier(0);   // keep write phase after compute
            write_tile(b ^ 1);       // data for u+1 (vmcnt wait here)
            if (u < 126) load_tile(u + 2);
            asm volatile("s_waitcnt lgkmcnt(0)" ::: "memory");
            __builtin_amdgcn_s_barrier();        // no vmcnt drain: loads in flight
        }
    }
}

// K3: h_out = relu(S + sum of 8 msg partials)   (float4, 256 blocks x 256 thr)
__global__ __launch_bounds__(256) void relu_kernel(
    const float* __restrict__ S, const float* __restrict__ msg, float* __restrict__ hout)
{
    int i = blockIdx.x * 256 + threadIdx.x;   // float4 index, NH/4 total
    float4 s = ((const float4*)S)[i];
    #pragma unroll
    for (int p = 0; p < NPART; ++p) {
        float4 m = ((const float4*)(msg + (size_t)p * NH))[i];
        s.x += m.x; s.y += m.y; s.z += m.z; s.w += m.w;
    }
    float4 o;
    o.x = fmaxf(s.x, 0.f); o.y = fmaxf(s.y, 0.f);
    o.z = fmaxf(s.z, 0.f); o.w = fmaxf(s.w, 0.f);
    ((float4*)hout)[i] = o;
}

// K4: gather with pad-row -> 0
__global__ __launch_bounds__(256) void gather_kernel(
    const float* __restrict__ h2, const int* __restrict__ kw, float* __restrict__ out)
{
    int e = blockIdx.x * 256 + threadIdx.x;   // 131072 total
    int ki = e >> 6, d = e & 63;
    int id = kw[ki];
    out[e] = ((unsigned)id < (unsigned)N_NODES) ? h2[(size_t)id * HID + d] : 0.f;
}

extern "C" void kernel_launch(void* const* d_in, const int* in_sizes, int n_in,
                              void* d_out, int out_size, void* d_ws, size_t ws_size,
                              hipStream_t stream) {
    const float* node_embed = (const float*)d_in[0];   // (4097, 64)
    const float* w_self     = (const float*)d_in[1];   // (2, 64, 64)
    const float* w_rel      = (const float*)d_in[2];   // (2, 8, 64, 64)
    const float* rel_adj    = (const float*)d_in[3];   // (8, 4096, 4096)
    const int*   kw         = (const int*)d_in[4];     // (64, 32)
    float* out = (float*)d_out;                        // (64, 32, 64) fp32

    // workspace carve (~15 MB)
    float* msg = (float*)d_ws;                       // NPART * NH f32 partials
    float* S   = msg + NPART * NH;                   // NH f32
    float* h1  = S + NH;                             // NH f32
    float* h2  = h1 + NH;                            // NH f32
    short* BT  = (short*)(h2 + NH);                  // 8*64*4096 bf16

    const float* hin = node_embed;   // layer 0 reads rows 0..4095 only
    float* houts[2] = {h1, h2};
    for (int l = 0; l < 2; ++l) {
        proj_kernel<<<dim3(64, 9), 256, 0, stream>>>(
            hin, w_self + (size_t)l * 64 * 64, w_rel + (size_t)l * 8 * 64 * 64, S, BT);
        gemm_kernel<<<512, 256, 0, stream>>>(rel_adj, BT, msg);
        relu_kernel<<<256, 256, 0, stream>>>(S, msg, houts[l]);
        hin = houts[l];
    }
    gather_kernel<<<512, 256, 0, stream>>>(h2, kw, out);
}